// Round 18
// baseline (256.833 us; speedup 1.0000x reference)
//
#include <hip/hip_runtime.h>
#include <hip/hip_bf16.h>

#define S_LEN 2048
#define HID_D 2048
#define NH 16
#define NKV 4
#define HD 128
#define BATCH 2

typedef __hip_bfloat16 bf16;
using f32x4 = __attribute__((ext_vector_type(4))) float;
using s16x8 = __attribute__((ext_vector_type(8))) short;

__device__ __forceinline__ f32x4 mfma_16x16x32(s16x8 a, s16x8 b, f32x4 c) {
  return __builtin_amdgcn_mfma_f32_16x16x32_bf16(a, b, c, 0, 0, 0);
}

__device__ __forceinline__ void gload16(const void* g, void* l) {
  __builtin_amdgcn_global_load_lds(
      (const __attribute__((address_space(1))) void*)g,
      (__attribute__((address_space(3))) void*)l, 16, 0, 0);
}

__device__ __forceinline__ unsigned int pk2bf(float a, float b) {
  __hip_bfloat16 lo = __float2bfloat16(a), hi = __float2bfloat16(b);
  return ((unsigned int)*(unsigned short*)&hi << 16) | *(unsigned short*)&lo;
}

// ---------------- elementwise convert f32 -> bf16 (x4 per thread) ----------------
__global__ __launch_bounds__(256) void convert_bf16_k(const float* __restrict__ in,
                                                      bf16* __restrict__ out) {
  int i = (blockIdx.x * 256 + threadIdx.x) * 4;
  float4 v = *(const float4*)&in[i];
  out[i + 0] = __float2bfloat16(v.x);
  out[i + 1] = __float2bfloat16(v.y);
  out[i + 2] = __float2bfloat16(v.z);
  out[i + 3] = __float2bfloat16(v.w);
}

// ---------------- tiled transpose + convert: in[K][N] f32 -> out[N][K] bf16 -------
__global__ __launch_bounds__(256) void transpose_convert_k(const float* __restrict__ in,
                                                           bf16* __restrict__ out,
                                                           int K, int N) {
  __shared__ float tile[32][33];
  int n0 = blockIdx.x * 32, k0 = blockIdx.y * 32;
  int tx = threadIdx.x, ty = threadIdx.y;
#pragma unroll
  for (int i = ty; i < 32; i += 8) tile[i][tx] = in[(size_t)(k0 + i) * N + n0 + tx];
  __syncthreads();
#pragma unroll
  for (int i = ty; i < 32; i += 8)
    out[(size_t)(n0 + i) * K + k0 + tx] = __float2bfloat16(tile[tx][i]);
}

// ---------------- 256x256 GEMM v2 (R16 verbatim): 64x128 wave tile; bf16 OUT -----
__global__ __launch_bounds__(512) void gemm256_k(const bf16* __restrict__ A,
                                                 const bf16* __restrict__ Bt,
                                                 bf16* __restrict__ C,
                                                 int M, int N, int K) {
  __shared__ bf16 Asm[2][256 * 64];
  __shared__ bf16 Bsm[2][256 * 64];
  const int tid = threadIdx.x;
  const int lane = tid & 63, wid = tid >> 6;
  const int fr = lane & 15, hi = lane >> 4;

  const int bid = blockIdx.y * gridDim.x + blockIdx.x;
  const int nwg = gridDim.x * gridDim.y;  // 192: %8==0, bijective
  const int swz = (bid & 7) * (nwg >> 3) + (bid >> 3);
  const int m0 = (swz % gridDim.x) * 256;
  const int n0 = (swz / gridDim.x) * 256;

  const bf16* Ag = A + (size_t)m0 * K;
  const bf16* Bg = Bt + (size_t)n0 * K;

  auto stageT = [&](const bf16* src, bf16* ldsBase, int k0) {
#pragma unroll
    for (int c = 0; c < 4; ++c) {
      int byte = tid * 16 + c * 8192;
      int row = byte >> 7;
      int col = byte & 127;
      int colSw = col ^ ((row & 7) << 4);
      gload16((const char*)(src + (size_t)row * K + k0) + colSw,
              (char*)ldsBase + byte);
    }
  };

  f32x4 acc[4][8];
#pragma unroll
  for (int m = 0; m < 4; ++m)
#pragma unroll
    for (int n = 0; n < 8; ++n) acc[m][n] = (f32x4){0.f, 0.f, 0.f, 0.f};

  const int r0 = (wid >> 1) * 64;
  const int c0 = (wid & 1) * 128;
  const int NT = K >> 6;

  stageT(Ag, &Asm[0][0], 0);
  stageT(Bg, &Bsm[0][0], 0);
  asm volatile("s_waitcnt vmcnt(0)" ::: "memory");
  __builtin_amdgcn_s_barrier();

  for (int t = 0; t < NT; ++t) {
    const int cur = t & 1;
    const int nxt = cur ^ 1;
    const int kn = (t + 1) << 6;
    const bool more = (t + 1) < NT;
#pragma unroll
    for (int p = 0; p < 2; ++p) {
      s16x8 af[4], bq[8];
#pragma unroll
      for (int m = 0; m < 4; ++m) {
        int r = r0 + m * 16 + fr;
        int cb = (p * 64 + hi * 16) ^ ((r & 7) << 4);
        af[m] = *(const s16x8*)((const char*)&Asm[cur][0] + r * 128 + cb);
      }
#pragma unroll
      for (int n = 0; n < 8; ++n) {
        int bn = c0 + n * 16 + fr;
        int cb = (p * 64 + hi * 16) ^ ((bn & 7) << 4);
        bq[n] = *(const s16x8*)((const char*)&Bsm[cur][0] + bn * 128 + cb);
      }
      if (p == 0) {
        if (more) {
          stageT(Ag, &Asm[nxt][0], kn);
          stageT(Bg, &Bsm[nxt][0], kn);
        }
      } else {
        asm volatile("s_waitcnt vmcnt(0)" ::: "memory");
      }
      __builtin_amdgcn_s_barrier();

      __builtin_amdgcn_s_setprio(1);
#pragma unroll
      for (int m = 0; m < 4; ++m)
#pragma unroll
        for (int n = 0; n < 8; ++n)
          acc[m][n] = mfma_16x16x32(af[m], bq[n], acc[m][n]);
      __builtin_amdgcn_s_setprio(0);
    }
  }

#pragma unroll
  for (int m = 0; m < 4; ++m)
#pragma unroll
    for (int n = 0; n < 8; ++n) {
      const int row = m0 + r0 + m * 16 + hi * 4;
      const int col = n0 + c0 + n * 16 + fr;
#pragma unroll
      for (int r = 0; r < 4; ++r)
        C[(size_t)(row + r) * N + col] = __float2bfloat16(acc[m][n][r]);
    }
}

// ---------------- 128x128 GEMM for Wo (R15 verbatim: proven) ---------------------
__global__ __launch_bounds__(256) void gemm128sq_k(const bf16* __restrict__ A,
                                                   const bf16* __restrict__ Bt,
                                                   float* __restrict__ C,
                                                   int M, int N, int K) {
  __shared__ bf16 Asm[2][128 * 64];
  __shared__ bf16 Bsm[2][128 * 64];
  const int tid = threadIdx.x;
  const int lane = tid & 63, wid = tid >> 6;
  const int fr = lane & 15, hi = lane >> 4;

  const int bid = blockIdx.y * gridDim.x + blockIdx.x;
  const int nwg = gridDim.x * gridDim.y;  // 512: %8==0, bijective
  const int swz = (bid & 7) * (nwg >> 3) + (bid >> 3);
  const int m0 = (swz % gridDim.x) * 128;
  const int n0 = (swz / gridDim.x) * 128;

  const bf16* Ag = A + (size_t)m0 * K;
  const bf16* Bg = Bt + (size_t)n0 * K;

  auto stageT = [&](const bf16* src, bf16* ldsBase, int k0) {
#pragma unroll
    for (int c = 0; c < 4; ++c) {
      int byte = tid * 16 + c * 4096;
      int row = byte >> 7;
      int col = byte & 127;
      int colSw = col ^ ((row & 7) << 4);
      gload16((const char*)(src + (size_t)row * K + k0) + colSw,
              (char*)ldsBase + byte);
    }
  };

  f32x4 acc[4][4];
#pragma unroll
  for (int m = 0; m < 4; ++m)
#pragma unroll
    for (int n = 0; n < 4; ++n) acc[m][n] = (f32x4){0.f, 0.f, 0.f, 0.f};

  const int r0 = (wid >> 1) * 64;
  const int c0 = (wid & 1) * 64;
  const int NT = K >> 6;

  stageT(Ag, &Asm[0][0], 0);
  stageT(Bg, &Bsm[0][0], 0);
  asm volatile("s_waitcnt vmcnt(0)" ::: "memory");
  __builtin_amdgcn_s_barrier();

  for (int t = 0; t < NT; ++t) {
    const int cur = t & 1;
    const int nxt = cur ^ 1;
    const int kn = (t + 1) << 6;
    const bool more = (t + 1) < NT;
#pragma unroll
    for (int p = 0; p < 2; ++p) {
      s16x8 af[4], bq[4];
#pragma unroll
      for (int m = 0; m < 4; ++m) {
        int r = r0 + m * 16 + fr;
        int cb = (p * 64 + hi * 16) ^ ((r & 7) << 4);
        af[m] = *(const s16x8*)((const char*)&Asm[cur][0] + r * 128 + cb);
      }
#pragma unroll
      for (int n = 0; n < 4; ++n) {
        int bn = c0 + n * 16 + fr;
        int cb = (p * 64 + hi * 16) ^ ((bn & 7) << 4);
        bq[n] = *(const s16x8*)((const char*)&Bsm[cur][0] + bn * 128 + cb);
      }
      if (p == 0) {
        if (more) {
          stageT(Ag, &Asm[nxt][0], kn);
          stageT(Bg, &Bsm[nxt][0], kn);
        }
      } else {
        asm volatile("s_waitcnt vmcnt(0)" ::: "memory");
      }
      __builtin_amdgcn_s_barrier();

      __builtin_amdgcn_s_setprio(1);
#pragma unroll
      for (int m = 0; m < 4; ++m)
#pragma unroll
        for (int n = 0; n < 4; ++n)
          acc[m][n] = mfma_16x16x32(af[m], bq[n], acc[m][n]);
      __builtin_amdgcn_s_setprio(0);
    }
  }

#pragma unroll
  for (int m = 0; m < 4; ++m)
#pragma unroll
    for (int n = 0; n < 4; ++n) {
      const int row = m0 + r0 + m * 16 + hi * 4;
      const int col = n0 + c0 + n * 16 + fr;
#pragma unroll
      for (int r = 0; r < 4; ++r)
        C[(size_t)(row + r) * N + col] = acc[m][n][r];
    }
}

// ---------------- RoPE for Q (bf16 in, pre-scaled by (1/sqrt(HD))*log2(e)) -------
__global__ __launch_bounds__(256) void rope_q_k(const bf16* __restrict__ qkv,
                                                const int* __restrict__ pos_ids,
                                                bf16* __restrict__ Q) {
  int idx = blockIdx.x * 256 + threadIdx.x;
  int i = idx & 63;
  int h = (idx >> 6) & 15;
  int s = (idx >> 10) & 2047;
  int b = idx >> 21;
  const float kscale = 0.12751841418861862f;  // (1/sqrt(128)) * log2(e)
  float pos = (float)pos_ids[b * S_LEN + s];
  float freq = exp2f((float)i * -0.31143075889569023f);
  float ang = pos * freq;
  float sn, cs;
  sincosf(ang, &sn, &cs);
  const bf16* src = qkv + (size_t)(b * S_LEN + s) * 3072 + h * HD + 2 * i;
  float e = __bfloat162float(src[0]), o = __bfloat162float(src[1]);
  bf16* dst = Q + ((size_t)(b * NH + h) * S_LEN + s) * HD + 2 * i;
  dst[0] = __float2bfloat16((e * cs - o * sn) * kscale);
  dst[1] = __float2bfloat16((e * sn + o * cs) * kscale);
}

// ---------------- RoPE for K (bf16 in) -------------------------------------------
__global__ __launch_bounds__(256) void rope_k_k(const bf16* __restrict__ qkv,
                                                const int* __restrict__ pos_ids,
                                                bf16* __restrict__ Kd) {
  int idx = blockIdx.x * 256 + threadIdx.x;
  int i = idx & 63;
  int kvh = (idx >> 6) & 3;
  int s = (idx >> 8) & 2047;
  int b = idx >> 19;
  float pos = (float)pos_ids[b * S_LEN + s];
  float freq = exp2f((float)i * -0.31143075889569023f);
  float ang = pos * freq;
  float sn, cs;
  sincosf(ang, &sn, &cs);
  const bf16* src = qkv + (size_t)(b * S_LEN + s) * 3072 + 2048 + kvh * HD + 2 * i;
  float e = __bfloat162float(src[0]), o = __bfloat162float(src[1]);
  bf16* dst = Kd + ((size_t)(b * NKV + kvh) * S_LEN + s) * HD + 2 * i;
  dst[0] = __float2bfloat16(e * cs - o * sn);
  dst[1] = __float2bfloat16(e * sn + o * cs);
}

// ---------------- V transpose via LDS tile (bf16 in, coalesced both sides) -------
__global__ __launch_bounds__(256) void v_trans_k(const bf16* __restrict__ qkv,
                                                 bf16* __restrict__ Vt) {
  __shared__ unsigned short tile[32][33];
  const int tx = threadIdx.x, ty = threadIdx.y;
  const int s0 = blockIdx.x * 32;
  const int d0 = blockIdx.y * 32;
  const int b = blockIdx.z >> 2, kvh = blockIdx.z & 3;
  const unsigned short* src = (const unsigned short*)qkv + 2560 + kvh * HD;
#pragma unroll
  for (int i = ty; i < 32; i += 8)
    tile[i][tx] = src[(size_t)(b * S_LEN + s0 + i) * 3072 + d0 + tx];
  __syncthreads();
  unsigned short* dst = (unsigned short*)Vt + (size_t)(b * NKV + kvh) * HD * S_LEN;
#pragma unroll
  for (int i = ty; i < 32; i += 8)
    dst[(size_t)(d0 + i) * S_LEN + s0 + tx] = tile[tx][i];
}

// ---------------- causal flash attention v13 -------------------------------------
// Reuse-2 with only PROVEN pieces. Wave owns 32 q-rows (each K/V fragment read
// feeds 2 MFMAs: 18 reads / 32 MFMAs vs v9's 34/32). 4 waves = 128-row tile, NO
// pairing, grid (16,NH,B)=512 longest-first (R11's proven grid). KVBLK=32 keeps
// LDS at 42KB -> 2-3 blocks/CU (R13's 80KB trap avoided). Layouts from the XOR
// family only (R17's 1040B padding was a 4-bank-shift disaster, 9.9M conflicts):
//   K: 32x256B rows, swizzle ((row>>1)&7)<<4 (8 lanes/slot, same algebra as v9)
//   V: 2 d-rows packed per 128B line, swizzle ((line&7)<<4)
//   P: 80B stride (16B-aligned reads, 8-slot spread; b32 stores 2-way = free)
// All staging via gload16 linear-dest + pre-swizzled global source (m173).
__global__ __launch_bounds__(256) void attn_k(const bf16* __restrict__ Q,
                                              const bf16* __restrict__ K,
                                              const bf16* __restrict__ Vt,
                                              bf16* __restrict__ Aout) {
  __shared__ __align__(16) char KsB[2][8192];   // 32 rows x 256B, swizzled
  __shared__ __align__(16) char VsB[2][8192];   // 64 lines x 128B (2 d-rows/line)
  __shared__ __align__(16) char PsB[4][2560];   // per wave: 32 rows x 80B

  const int tid = threadIdx.x;
  const int lane = tid & 63, wid = tid >> 6;
  const int fr = lane & 15, hi = lane >> 4;
  const int qb = 15 - blockIdx.x;               // longest first (LPT)
  const int h = blockIdx.y, b = blockIdx.z;
  const int kvh = h >> 2;
  const bf16* Qh = Q + (size_t)(b * NH + h) * S_LEN * HD;
  const bf16* Kh = K + (size_t)(b * NKV + kvh) * S_LEN * HD;
  const bf16* Vh = Vt + (size_t)(b * NKV + kvh) * HD * S_LEN;

  const int q0w = qb * 128 + wid * 32;          // wave's 32 rows
  const int nsteps = 4 * qb + 4;

  // K stage: linear dest byte X; source col pre-swizzled to match read
  auto stageK = [&](int bufi, int kv0) {
#pragma unroll
    for (int c = 0; c < 2; ++c) {
      int X = tid * 16 + c * 4096;
      int row = X >> 8, col = X & 255;
      int colSw = col ^ (((row >> 1) & 7) << 4);
      gload16((const char*)Kh + (size_t)(kv0 + row) * 256 + colSw,
              &KsB[bufi][0] + X);
    }
  };
  // V stage: dest (line,off) holds source V[2*line + ((off^sw)>>6)][(off^sw)&63]
  auto stageV = [&](int bufi, int kv0) {
#pragma unroll
    for (int c = 0; c < 2; ++c) {
      int X = tid * 16 + c * 4096;
      int line = X >> 7, off = X & 127;
      int offS = off ^ ((line & 7) << 4);
      int d = 2 * line + (offS >> 6);
      gload16((const char*)Vh + (size_t)d * (S_LEN * 2) + (size_t)kv0 * 2 + (offS & 63),
              &VsB[bufi][0] + X);
    }
  };

  s16x8 qf[2][4];
#pragma unroll
  for (int u = 0; u < 2; ++u)
#pragma unroll
    for (int ks = 0; ks < 4; ++ks)
      qf[u][ks] = *(const s16x8*)&Qh[(size_t)(q0w + u * 16 + fr) * HD + ks * 32 + hi * 8];

  f32x4 o[2][8];
#pragma unroll
  for (int u = 0; u < 2; ++u)
#pragma unroll
    for (int ds = 0; ds < 8; ++ds) o[u][ds] = (f32x4){0.f, 0.f, 0.f, 0.f};
  float lacc[2][4];
#pragma unroll
  for (int u = 0; u < 2; ++u)
#pragma unroll
    for (int r = 0; r < 4; ++r) lacc[u][r] = 0.f;

  stageK(0, 0);
  stageV(0, 0);
  __syncthreads();

  int buf = 0;
  for (int s = 0; s < nsteps; ++s) {
    const int kv0 = s * 32;
    if (s + 1 < nsteps) {
      stageK(buf ^ 1, kv0 + 32);
      stageV(buf ^ 1, kv0 + 32);
    }

    if (kv0 <= q0w) {                 // wave has unmasked rows this step
      const bool diag = (kv0 == q0w); // wave-uniform
      // ---- QK^T: 8 kf reads, 16 MFMAs (each kf feeds both q-frags) ----
      f32x4 sg[2][2];
#pragma unroll
      for (int u = 0; u < 2; ++u)
#pragma unroll
        for (int kvi = 0; kvi < 2; ++kvi) sg[u][kvi] = (f32x4){0.f, 0.f, 0.f, 0.f};
#pragma unroll
      for (int kvi = 0; kvi < 2; ++kvi) {
        const int row = 2 * fr + kvi;          // sg[kvi] col fr <-> K row 2fr+kvi
        const char* kb_ = &KsB[buf][0] + row * 256;
        const int sw = ((row >> 1) & 7) << 4;  // = (fr&7)<<4
#pragma unroll
        for (int ks = 0; ks < 4; ++ks) {
          s16x8 kf = *(const s16x8*)(kb_ + ((ks * 64 + hi * 16) ^ sw));
          sg[0][kvi] = mfma_16x16x32(qf[0][ks], kf, sg[0][kvi]);
          sg[1][kvi] = mfma_16x16x32(qf[1][ks], kf, sg[1][kvi]);
        }
      }

      // ---- fixed-ref softmax + packed b32 P store ----
#pragma unroll
      for (int u = 0; u < 2; ++u)
#pragma unroll
        for (int r = 0; r < 4; ++r) {
          float p0 = __builtin_exp2f(sg[u][0][r]);
          float p1 = __builtin_exp2f(sg[u][1][r]);
          if (diag) {   // kv-rel = 2fr+kvi vs row-rel
            const int rowrel = u * 16 + hi * 4 + r;
            p0 = (2 * fr <= rowrel) ? p0 : 0.f;
            p1 = (2 * fr + 1 <= rowrel) ? p1 : 0.f;
          }
          lacc[u][r] += p0 + p1;
          const int prow = u * 16 + hi * 4 + r;
          *(unsigned int*)(&PsB[wid][0] + prow * 80 + fr * 4) = pk2bf(p0, p1);
        }
      __builtin_amdgcn_wave_barrier();

      s16x8 pf[2];
#pragma unroll
      for (int u = 0; u < 2; ++u)
        pf[u] = *(const s16x8*)(&PsB[wid][0] + (u * 16 + fr) * 80 + hi * 16);
      __builtin_amdgcn_wave_barrier();

      // ---- PV: 8 vf reads, 16 MFMAs (each vf feeds both q-frags) ----
#pragma unroll
      for (int ds = 0; ds < 8; ++ds) {
        const int d = ds * 16 + fr;
        const int line = d >> 1;
        const int off = ((d & 1) * 64 + hi * 16) ^ ((line & 7) << 4);
        s16x8 vf = *(const s16x8*)(&VsB[buf][0] + line * 128 + off);
        o[0][ds] = mfma_16x16x32(pf[0], vf, o[0][ds]);
        o[1][ds] = mfma_16x16x32(pf[1], vf, o[1][ds]);
      }
    }

    __syncthreads();   // drains staging gloads; separates buffer reuse
    buf ^= 1;
  }

  // ---- epilogue: reduce l across 16-lane group, normalize, store ----
#pragma unroll
  for (int u = 0; u < 2; ++u)
#pragma unroll
    for (int r = 0; r < 4; ++r) {
      float l = lacc[u][r];
      l += __shfl_xor(l, 1, 16);
      l += __shfl_xor(l, 2, 16);
      l += __shfl_xor(l, 4, 16);
      l += __shfl_xor(l, 8, 16);
      float inv = 1.0f / l;
      const int srow = q0w + u * 16 + hi * 4 + r;
      bf16* orow = Aout + ((size_t)b * S_LEN + srow) * HID_D + h * HD;
#pragma unroll
      for (int ds = 0; ds < 8; ++ds)
        orow[ds * 16 + fr] = __float2bfloat16(o[u][ds][r] * inv);
    }
}

extern "C" void kernel_launch(void* const* d_in, const int* in_sizes, int n_in,
                              void* d_out, int out_size, void* d_ws, size_t ws_size,
                              hipStream_t stream) {
  const float* x = (const float*)d_in[0];
  const int* pos = (const int*)d_in[1];
  // d_in[2] attention_mask: known causal, applied analytically
  const float* Wq = (const float*)d_in[3];
  const float* Wk = (const float*)d_in[4];
  const float* Wv = (const float*)d_in[5];
  const float* Wo = (const float*)d_in[6];
  float* out = (float*)d_out;

  char* ws = (char*)d_ws;
  size_t off = 0;
  auto alloc = [&](size_t bytes) {
    char* p = ws + off;
    off += (bytes + 255) & ~(size_t)255;
    return p;
  };
  bf16* xb = (bf16*)alloc((size_t)4096 * 2048 * 2);
  bf16* WqkvT = (bf16*)alloc((size_t)3072 * 2048 * 2);
  bf16* WoT = (bf16*)alloc((size_t)2048 * 2048 * 2);
  bf16* qkv = (bf16*)alloc((size_t)4096 * 3072 * 2);   // bf16 intermediate
  bf16* Qb = (bf16*)alloc((size_t)BATCH * NH * S_LEN * HD * 2);
  bf16* Kb = (bf16*)alloc((size_t)BATCH * NKV * S_LEN * HD * 2);
  bf16* Vtb = (bf16*)alloc((size_t)BATCH * NKV * HD * S_LEN * 2);
  bf16* aout = (bf16*)qkv;  // alias: qkv dead after rope/v_trans

  convert_bf16_k<<<8192, 256, 0, stream>>>(x, xb);
  dim3 tb(32, 8);
  transpose_convert_k<<<dim3(64, 64), tb, 0, stream>>>(Wq, WqkvT, 2048, 2048);
  transpose_convert_k<<<dim3(16, 64), tb, 0, stream>>>(Wk, WqkvT + (size_t)2048 * 2048, 2048, 512);
  transpose_convert_k<<<dim3(16, 64), tb, 0, stream>>>(Wv, WqkvT + (size_t)2560 * 2048, 2048, 512);
  transpose_convert_k<<<dim3(64, 64), tb, 0, stream>>>(Wo, WoT, 2048, 2048);

  gemm256_k<<<dim3(16, 12), 512, 0, stream>>>(xb, WqkvT, qkv, 4096, 3072, 2048);

  rope_q_k<<<16384, 256, 0, stream>>>(qkv, pos, Qb);
  rope_k_k<<<4096, 256, 0, stream>>>(qkv, pos, Kb);
  v_trans_k<<<dim3(64, 4, 8), tb, 0, stream>>>(qkv, Vtb);

  attn_k<<<dim3(16, NH, BATCH), 256, 0, stream>>>(Qb, Kb, Vtb, aout);

  gemm128sq_k<<<dim3(32, 16), 256, 0, stream>>>(aout, WoT, out, 4096, 2048, 2048);
}

// Round 19
// 211.096 us; speedup vs baseline: 1.2167x; 1.2167x over previous
//
#include <hip/hip_runtime.h>
#include <hip/hip_bf16.h>

#define S_LEN 2048
#define HID_D 2048
#define NH 16
#define NKV 4
#define HD 128
#define BATCH 2

typedef __hip_bfloat16 bf16;
using f32x4 = __attribute__((ext_vector_type(4))) float;
using s16x8 = __attribute__((ext_vector_type(8))) short;

struct TrueT { static constexpr bool value = true; };
struct FalseT { static constexpr bool value = false; };

__device__ __forceinline__ f32x4 mfma_16x16x32(s16x8 a, s16x8 b, f32x4 c) {
  return __builtin_amdgcn_mfma_f32_16x16x32_bf16(a, b, c, 0, 0, 0);
}

__device__ __forceinline__ void gload16(const void* g, void* l) {
  __builtin_amdgcn_global_load_lds(
      (const __attribute__((address_space(1))) void*)g,
      (__attribute__((address_space(3))) void*)l, 16, 0, 0);
}

__device__ __forceinline__ unsigned int pk2bf(float a, float b) {
  __hip_bfloat16 lo = __float2bfloat16(a), hi = __float2bfloat16(b);
  return ((unsigned int)*(unsigned short*)&hi << 16) | *(unsigned short*)&lo;
}

// ---------------- elementwise convert f32 -> bf16 (x4 per thread) ----------------
__global__ __launch_bounds__(256) void convert_bf16_k(const float* __restrict__ in,
                                                      bf16* __restrict__ out) {
  int i = (blockIdx.x * 256 + threadIdx.x) * 4;
  float4 v = *(const float4*)&in[i];
  out[i + 0] = __float2bfloat16(v.x);
  out[i + 1] = __float2bfloat16(v.y);
  out[i + 2] = __float2bfloat16(v.z);
  out[i + 3] = __float2bfloat16(v.w);
}

// ---------------- tiled transpose + convert: in[K][N] f32 -> out[N][K] bf16 -------
__global__ __launch_bounds__(256) void transpose_convert_k(const float* __restrict__ in,
                                                           bf16* __restrict__ out,
                                                           int K, int N) {
  __shared__ float tile[32][33];
  int n0 = blockIdx.x * 32, k0 = blockIdx.y * 32;
  int tx = threadIdx.x, ty = threadIdx.y;
#pragma unroll
  for (int i = ty; i < 32; i += 8) tile[i][tx] = in[(size_t)(k0 + i) * N + n0 + tx];
  __syncthreads();
#pragma unroll
  for (int i = ty; i < 32; i += 8)
    out[(size_t)(n0 + i) * K + k0 + tx] = __float2bfloat16(tile[tx][i]);
}

// ---------------- 128x128 GEMM, bf16 out (QKV): proven gemm128sq schedule --------
// prologue: stage A0+B0 (8 loads), vmcnt(0), barrier.
// p0 of t: ds_read ks=0 (tile t landed by induction); stage A[t+1]+B[t+1];
//          barrier; 16 MFMA.
// p1 of t: ds_read ks=1; vmcnt(0); barrier; 16 MFMA.
// Full-fill grid 32x24=768 blocks (vs 256^2-tile's 192 at 1 block/CU).
__global__ __launch_bounds__(256) void gemm128b_k(const bf16* __restrict__ A,
                                                  const bf16* __restrict__ Bt,
                                                  bf16* __restrict__ C,
                                                  int M, int N, int K) {
  __shared__ bf16 Asm[2][128 * 64];
  __shared__ bf16 Bsm[2][128 * 64];
  const int tid = threadIdx.x;
  const int lane = tid & 63, wid = tid >> 6;
  const int fr = lane & 15, hi = lane >> 4;

  const int bid = blockIdx.y * gridDim.x + blockIdx.x;
  const int nwg = gridDim.x * gridDim.y;  // 768: %8==0, bijective
  const int swz = (bid & 7) * (nwg >> 3) + (bid >> 3);
  const int m0 = (swz % gridDim.x) * 128;
  const int n0 = (swz / gridDim.x) * 128;

  const bf16* Ag = A + (size_t)m0 * K;
  const bf16* Bg = Bt + (size_t)n0 * K;

  auto stageT = [&](const bf16* src, bf16* ldsBase, int k0) {
#pragma unroll
    for (int c = 0; c < 4; ++c) {
      int byte = tid * 16 + c * 4096;
      int row = byte >> 7;
      int col = byte & 127;
      int colSw = col ^ ((row & 7) << 4);
      gload16((const char*)(src + (size_t)row * K + k0) + colSw,
              (char*)ldsBase + byte);
    }
  };

  f32x4 acc[4][4];
#pragma unroll
  for (int m = 0; m < 4; ++m)
#pragma unroll
    for (int n = 0; n < 4; ++n) acc[m][n] = (f32x4){0.f, 0.f, 0.f, 0.f};

  const int r0 = (wid >> 1) * 64;
  const int c0 = (wid & 1) * 64;
  const int NT = K >> 6;

  stageT(Ag, &Asm[0][0], 0);
  stageT(Bg, &Bsm[0][0], 0);
  asm volatile("s_waitcnt vmcnt(0)" ::: "memory");
  __builtin_amdgcn_s_barrier();

  for (int t = 0; t < NT; ++t) {
    const int cur = t & 1;
    const int nxt = cur ^ 1;
    const int kn = (t + 1) << 6;
    const bool more = (t + 1) < NT;
#pragma unroll
    for (int p = 0; p < 2; ++p) {
      s16x8 af[4], bq[4];
#pragma unroll
      for (int m = 0; m < 4; ++m) {
        int r = r0 + m * 16 + fr;
        int cb = (p * 64 + hi * 16) ^ ((r & 7) << 4);
        af[m] = *(const s16x8*)((const char*)&Asm[cur][0] + r * 128 + cb);
      }
#pragma unroll
      for (int n = 0; n < 4; ++n) {
        int bn = c0 + n * 16 + fr;
        int cb = (p * 64 + hi * 16) ^ ((bn & 7) << 4);
        bq[n] = *(const s16x8*)((const char*)&Bsm[cur][0] + bn * 128 + cb);
      }
      if (p == 0) {
        if (more) {
          stageT(Ag, &Asm[nxt][0], kn);
          stageT(Bg, &Bsm[nxt][0], kn);
        }
      } else {
        asm volatile("s_waitcnt vmcnt(0)" ::: "memory");
      }
      __builtin_amdgcn_s_barrier();

      __builtin_amdgcn_s_setprio(1);
#pragma unroll
      for (int m = 0; m < 4; ++m)
#pragma unroll
        for (int n = 0; n < 4; ++n)
          acc[m][n] = mfma_16x16x32(af[m], bq[n], acc[m][n]);
      __builtin_amdgcn_s_setprio(0);
    }
  }

#pragma unroll
  for (int m = 0; m < 4; ++m)
#pragma unroll
    for (int n = 0; n < 4; ++n) {
      const int row = m0 + r0 + m * 16 + hi * 4;
      const int col = n0 + c0 + n * 16 + fr;
#pragma unroll
      for (int r = 0; r < 4; ++r)
        C[(size_t)(row + r) * N + col] = __float2bfloat16(acc[m][n][r]);
    }
}

// ---------------- 128x128 GEMM for Wo (R15 verbatim: proven), f32 out ------------
__global__ __launch_bounds__(256) void gemm128sq_k(const bf16* __restrict__ A,
                                                   const bf16* __restrict__ Bt,
                                                   float* __restrict__ C,
                                                   int M, int N, int K) {
  __shared__ bf16 Asm[2][128 * 64];
  __shared__ bf16 Bsm[2][128 * 64];
  const int tid = threadIdx.x;
  const int lane = tid & 63, wid = tid >> 6;
  const int fr = lane & 15, hi = lane >> 4;

  const int bid = blockIdx.y * gridDim.x + blockIdx.x;
  const int nwg = gridDim.x * gridDim.y;  // 512: %8==0, bijective
  const int swz = (bid & 7) * (nwg >> 3) + (bid >> 3);
  const int m0 = (swz % gridDim.x) * 128;
  const int n0 = (swz / gridDim.x) * 128;

  const bf16* Ag = A + (size_t)m0 * K;
  const bf16* Bg = Bt + (size_t)n0 * K;

  auto stageT = [&](const bf16* src, bf16* ldsBase, int k0) {
#pragma unroll
    for (int c = 0; c < 4; ++c) {
      int byte = tid * 16 + c * 4096;
      int row = byte >> 7;
      int col = byte & 127;
      int colSw = col ^ ((row & 7) << 4);
      gload16((const char*)(src + (size_t)row * K + k0) + colSw,
              (char*)ldsBase + byte);
    }
  };

  f32x4 acc[4][4];
#pragma unroll
  for (int m = 0; m < 4; ++m)
#pragma unroll
    for (int n = 0; n < 4; ++n) acc[m][n] = (f32x4){0.f, 0.f, 0.f, 0.f};

  const int r0 = (wid >> 1) * 64;
  const int c0 = (wid & 1) * 64;
  const int NT = K >> 6;

  stageT(Ag, &Asm[0][0], 0);
  stageT(Bg, &Bsm[0][0], 0);
  asm volatile("s_waitcnt vmcnt(0)" ::: "memory");
  __builtin_amdgcn_s_barrier();

  for (int t = 0; t < NT; ++t) {
    const int cur = t & 1;
    const int nxt = cur ^ 1;
    const int kn = (t + 1) << 6;
    const bool more = (t + 1) < NT;
#pragma unroll
    for (int p = 0; p < 2; ++p) {
      s16x8 af[4], bq[4];
#pragma unroll
      for (int m = 0; m < 4; ++m) {
        int r = r0 + m * 16 + fr;
        int cb = (p * 64 + hi * 16) ^ ((r & 7) << 4);
        af[m] = *(const s16x8*)((const char*)&Asm[cur][0] + r * 128 + cb);
      }
#pragma unroll
      for (int n = 0; n < 4; ++n) {
        int bn = c0 + n * 16 + fr;
        int cb = (p * 64 + hi * 16) ^ ((bn & 7) << 4);
        bq[n] = *(const s16x8*)((const char*)&Bsm[cur][0] + bn * 128 + cb);
      }
      if (p == 0) {
        if (more) {
          stageT(Ag, &Asm[nxt][0], kn);
          stageT(Bg, &Bsm[nxt][0], kn);
        }
      } else {
        asm volatile("s_waitcnt vmcnt(0)" ::: "memory");
      }
      __builtin_amdgcn_s_barrier();

      __builtin_amdgcn_s_setprio(1);
#pragma unroll
      for (int m = 0; m < 4; ++m)
#pragma unroll
        for (int n = 0; n < 4; ++n)
          acc[m][n] = mfma_16x16x32(af[m], bq[n], acc[m][n]);
      __builtin_amdgcn_s_setprio(0);
    }
  }

#pragma unroll
  for (int m = 0; m < 4; ++m)
#pragma unroll
    for (int n = 0; n < 4; ++n) {
      const int row = m0 + r0 + m * 16 + hi * 4;
      const int col = n0 + c0 + n * 16 + fr;
#pragma unroll
      for (int r = 0; r < 4; ++r)
        C[(size_t)(row + r) * N + col] = acc[m][n][r];
    }
}

// ---------------- RoPE for Q (bf16 in, pre-scaled by (1/sqrt(HD))*log2(e)) -------
__global__ __launch_bounds__(256) void rope_q_k(const bf16* __restrict__ qkv,
                                                const int* __restrict__ pos_ids,
                                                bf16* __restrict__ Q) {
  int idx = blockIdx.x * 256 + threadIdx.x;
  int i = idx & 63;
  int h = (idx >> 6) & 15;
  int s = (idx >> 10) & 2047;
  int b = idx >> 21;
  const float kscale = 0.12751841418861862f;  // (1/sqrt(128)) * log2(e)
  float pos = (float)pos_ids[b * S_LEN + s];
  float freq = exp2f((float)i * -0.31143075889569023f);
  float ang = pos * freq;
  float sn, cs;
  sincosf(ang, &sn, &cs);
  const bf16* src = qkv + (size_t)(b * S_LEN + s) * 3072 + h * HD + 2 * i;
  float e = __bfloat162float(src[0]), o = __bfloat162float(src[1]);
  bf16* dst = Q + ((size_t)(b * NH + h) * S_LEN + s) * HD + 2 * i;
  dst[0] = __float2bfloat16((e * cs - o * sn) * kscale);
  dst[1] = __float2bfloat16((e * sn + o * cs) * kscale);
}

// ---------------- RoPE for K (bf16 in) -------------------------------------------
__global__ __launch_bounds__(256) void rope_k_k(const bf16* __restrict__ qkv,
                                                const int* __restrict__ pos_ids,
                                                bf16* __restrict__ Kd) {
  int idx = blockIdx.x * 256 + threadIdx.x;
  int i = idx & 63;
  int kvh = (idx >> 6) & 3;
  int s = (idx >> 8) & 2047;
  int b = idx >> 19;
  float pos = (float)pos_ids[b * S_LEN + s];
  float freq = exp2f((float)i * -0.31143075889569023f);
  float ang = pos * freq;
  float sn, cs;
  sincosf(ang, &sn, &cs);
  const bf16* src = qkv + (size_t)(b * S_LEN + s) * 3072 + 2048 + kvh * HD + 2 * i;
  float e = __bfloat162float(src[0]), o = __bfloat162float(src[1]);
  bf16* dst = Kd + ((size_t)(b * NKV + kvh) * S_LEN + s) * HD + 2 * i;
  dst[0] = __float2bfloat16(e * cs - o * sn);
  dst[1] = __float2bfloat16(e * sn + o * cs);
}

// ---------------- V transpose via LDS tile (bf16 in, coalesced both sides) -------
__global__ __launch_bounds__(256) void v_trans_k(const bf16* __restrict__ qkv,
                                                 bf16* __restrict__ Vt) {
  __shared__ unsigned short tile[32][33];
  const int tx = threadIdx.x, ty = threadIdx.y;
  const int s0 = blockIdx.x * 32;
  const int d0 = blockIdx.y * 32;
  const int b = blockIdx.z >> 2, kvh = blockIdx.z & 3;
  const unsigned short* src = (const unsigned short*)qkv + 2560 + kvh * HD;
#pragma unroll
  for (int i = ty; i < 32; i += 8)
    tile[i][tx] = src[(size_t)(b * S_LEN + s0 + i) * 3072 + d0 + tx];
  __syncthreads();
  unsigned short* dst = (unsigned short*)Vt + (size_t)(b * NKV + kvh) * HD * S_LEN;
#pragma unroll
  for (int i = ty; i < 32; i += 8)
    dst[(size_t)(d0 + i) * S_LEN + s0 + tx] = tile[tx][i];
}

// ---------------- causal flash attention v9 (R11/R16 verbatim: proven 72us) ------
__global__ __launch_bounds__(256) void attn_k(const bf16* __restrict__ Q,
                                              const bf16* __restrict__ K,
                                              const bf16* __restrict__ Vt,
                                              bf16* __restrict__ Aout) {
  __shared__ bf16 Ks[2][64 * 128];
  __shared__ bf16 Vs[2][128 * 64];
  __shared__ bf16 Ps[4][16 * 64];

  const int lane = threadIdx.x & 63;
  const int wid = threadIdx.x >> 6;
  const int fr = lane & 15;
  const int hi = lane >> 4;
  const int pi = blockIdx.x, h = blockIdx.y, b = blockIdx.z;
  const int kvh = h >> 2;
  const bf16* Qh = Q + (size_t)(b * NH + h) * S_LEN * HD;
  const bf16* Kh = K + (size_t)(b * NKV + kvh) * S_LEN * HD;
  const bf16* Vh = Vt + (size_t)(b * NKV + kvh) * HD * S_LEN;

  const int oB = lane * 16;
  const int rinK = oB >> 8;
  const int rinV = oB >> 7;
  bf16* myP = &Ps[wid][0];
  const int pswz = (fr & 7) << 4;

  auto stageKV = [&](int bufi, int kv0) {
#pragma unroll
    for (int c = 0; c < 4; ++c) {
      int absr = wid * 16 + c * 4 + rinK;
      int colb = (oB & 255) ^ (((absr >> 2) & 7) << 4);  // matches K-read swizzle
      gload16((const char*)Kh + (size_t)(kv0 + absr) * 256 + colb,
              (char*)&Ks[bufi][0] + (wid * 16 + c * 4) * 256);
    }
#pragma unroll
    for (int c = 0; c < 4; ++c) {
      int absd = wid * 32 + c * 8 + rinV;
      int colb = (oB & 127) ^ ((absd & 7) << 4);
      gload16((const char*)Vh + (size_t)absd * (S_LEN * 2) + (size_t)kv0 * 2 + colb,
              (char*)&Vs[bufi][0] + (wid * 32 + c * 8) * 128);
    }
  };

#pragma unroll 1
  for (int t = 0; t < 2; ++t) {
    const int qb = t ? (31 - pi) : pi;
    const int q0w = qb * 64 + wid * 16;
    const int nsteps = qb + 1;

    s16x8 qf[4];
#pragma unroll
    for (int ks = 0; ks < 4; ++ks)
      qf[ks] = *(const s16x8*)&Qh[(size_t)(q0w + fr) * HD + ks * 32 + hi * 8];

    f32x4 o[8];
#pragma unroll
    for (int ds = 0; ds < 8; ++ds) o[ds] = (f32x4){0.f, 0.f, 0.f, 0.f};
    float lacc[4];
#pragma unroll
    for (int r = 0; r < 4; ++r) lacc[r] = 0.f;

    auto doStep = [&](int kv0, int bufc, auto LASTC) {
      constexpr bool LAST = decltype(LASTC)::value;
      f32x4 sg[4];
#pragma unroll
      for (int kv = 0; kv < 4; ++kv) {
        f32x4 a = (f32x4){0.f, 0.f, 0.f, 0.f};
        const int row = 4 * fr + kv;  // sg[kv] col fr <-> K row 4*fr+kv
#pragma unroll
        for (int ks = 0; ks < 4; ++ks) {
          int cb = (ks * 64 + hi * 16) ^ (((row >> 2) & 7) << 4);
          s16x8 kf = *(const s16x8*)((const char*)&Ks[bufc][0] + row * 256 + cb);
          a = mfma_16x16x32(qf[ks], kf, a);
        }
        sg[kv] = a;
      }

#pragma unroll
      for (int r = 0; r < 4; ++r) {
        float p0 = __builtin_exp2f(sg[0][r]);
        float p1 = __builtin_exp2f(sg[1][r]);
        float p2 = __builtin_exp2f(sg[2][r]);
        float p3 = __builtin_exp2f(sg[3][r]);
        if (LAST) {  // diagonal tile: k = kv0 + 4*fr + kv
          const int qrow = q0w + hi * 4 + r;
          const int kb = kv0 + 4 * fr;
          p0 = (kb <= qrow) ? p0 : 0.f;
          p1 = (kb + 1 <= qrow) ? p1 : 0.f;
          p2 = (kb + 2 <= qrow) ? p2 : 0.f;
          p3 = (kb + 3 <= qrow) ? p3 : 0.f;
        }
        lacc[r] += (p0 + p1) + (p2 + p3);
        const int prow = hi * 4 + r;
        uint2 pv;
        pv.x = pk2bf(p0, p1);
        pv.y = pk2bf(p2, p3);
        *(uint2*)((char*)myP + prow * 128 + ((fr * 8) ^ ((prow & 7) << 4))) = pv;
      }
      __builtin_amdgcn_wave_barrier();

      s16x8 pf[2];
#pragma unroll
      for (int g = 0; g < 2; ++g) {
        int cb = (g * 64 + hi * 16) ^ pswz;
        pf[g] = *(const s16x8*)((const char*)myP + fr * 128 + cb);
      }
      __builtin_amdgcn_wave_barrier();
#pragma unroll
      for (int ds = 0; ds < 8; ++ds) {
#pragma unroll
        for (int g = 0; g < 2; ++g) {
          int d = ds * 16 + fr;
          int cb = (g * 64 + hi * 16) ^ ((d & 7) << 4);
          s16x8 vf = *(const s16x8*)((const char*)&Vs[bufc][0] + d * 128 + cb);
          o[ds] = mfma_16x16x32(pf[g], vf, o[ds]);
        }
      }
    };

    int buf = 0;
    stageKV(0, 0);
    __syncthreads();

    for (int s = 0; s < nsteps - 1; ++s) {
      stageKV(buf ^ 1, s * 64 + 64);
      doStep(s * 64, buf, FalseT{});
      __syncthreads();
      buf ^= 1;
    }
    doStep((nsteps - 1) * 64, buf, TrueT{});
    __syncthreads();

#pragma unroll
    for (int r = 0; r < 4; ++r) {
      float l = lacc[r];
      l += __shfl_xor(l, 1, 16);
      l += __shfl_xor(l, 2, 16);
      l += __shfl_xor(l, 4, 16);
      l += __shfl_xor(l, 8, 16);
      float inv = 1.0f / l;
      const int srow = q0w + hi * 4 + r;
      bf16* orow = Aout + ((size_t)b * S_LEN + srow) * HID_D + h * HD;
#pragma unroll
      for (int ds = 0; ds < 8; ++ds)
        orow[ds * 16 + fr] = __float2bfloat16(o[ds][r] * inv);
    }
  }
}

extern "C" void kernel_launch(void* const* d_in, const int* in_sizes, int n_in,
                              void* d_out, int out_size, void* d_ws, size_t ws_size,
                              hipStream_t stream) {
  const float* x = (const float*)d_in[0];
  const int* pos = (const int*)d_in[1];
  // d_in[2] attention_mask: known causal, applied analytically
  const float* Wq = (const float*)d_in[3];
  const float* Wk = (const float*)d_in[4];
  const float* Wv = (const float*)d_in[5];
  const float* Wo = (const float*)d_in[6];
  float* out = (float*)d_out;

  char* ws = (char*)d_ws;
  size_t off = 0;
  auto alloc = [&](size_t bytes) {
    char* p = ws + off;
    off += (bytes + 255) & ~(size_t)255;
    return p;
  };
  bf16* xb = (bf16*)alloc((size_t)4096 * 2048 * 2);
  bf16* WqkvT = (bf16*)alloc((size_t)3072 * 2048 * 2);
  bf16* WoT = (bf16*)alloc((size_t)2048 * 2048 * 2);
  bf16* qkv = (bf16*)alloc((size_t)4096 * 3072 * 2);   // bf16 intermediate
  bf16* Qb = (bf16*)alloc((size_t)BATCH * NH * S_LEN * HD * 2);
  bf16* Kb = (bf16*)alloc((size_t)BATCH * NKV * S_LEN * HD * 2);
  bf16* Vtb = (bf16*)alloc((size_t)BATCH * NKV * HD * S_LEN * 2);
  bf16* aout = (bf16*)qkv;  // alias: qkv dead after rope/v_trans

  convert_bf16_k<<<8192, 256, 0, stream>>>(x, xb);
  dim3 tb(32, 8);
  transpose_convert_k<<<dim3(64, 64), tb, 0, stream>>>(Wq, WqkvT, 2048, 2048);
  transpose_convert_k<<<dim3(16, 64), tb, 0, stream>>>(Wk, WqkvT + (size_t)2048 * 2048, 2048, 512);
  transpose_convert_k<<<dim3(16, 64), tb, 0, stream>>>(Wv, WqkvT + (size_t)2560 * 2048, 2048, 512);
  transpose_convert_k<<<dim3(64, 64), tb, 0, stream>>>(Wo, WoT, 2048, 2048);

  gemm128b_k<<<dim3(32, 24), 256, 0, stream>>>(xb, WqkvT, qkv, 4096, 3072, 2048);

  rope_q_k<<<16384, 256, 0, stream>>>(qkv, pos, Qb);
  rope_k_k<<<4096, 256, 0, stream>>>(qkv, pos, Kb);
  v_trans_k<<<dim3(64, 4, 8), tb, 0, stream>>>(qkv, Vtb);

  attn_k<<<dim3(16, NH, BATCH), 256, 0, stream>>>(Qb, Kb, Vtb, aout);

  gemm128sq_k<<<dim3(32, 16), 256, 0, stream>>>(aout, WoT, out, 4096, 2048, 2048);
}

// Round 20
// 200.466 us; speedup vs baseline: 1.2812x; 1.0530x over previous
//
#include <hip/hip_runtime.h>
#include <hip/hip_bf16.h>

#define S_LEN 2048
#define HID_D 2048
#define NH 16
#define NKV 4
#define HD 128
#define BATCH 2

typedef __hip_bfloat16 bf16;
using f32x4 = __attribute__((ext_vector_type(4))) float;
using s16x8 = __attribute__((ext_vector_type(8))) short;

struct TrueT { static constexpr bool value = true; };
struct FalseT { static constexpr bool value = false; };

__device__ __forceinline__ f32x4 mfma_16x16x32(s16x8 a, s16x8 b, f32x4 c) {
  return __builtin_amdgcn_mfma_f32_16x16x32_bf16(a, b, c, 0, 0, 0);
}

__device__ __forceinline__ void gload16(const void* g, void* l) {
  __builtin_amdgcn_global_load_lds(
      (const __attribute__((address_space(1))) void*)g,
      (__attribute__((address_space(3))) void*)l, 16, 0, 0);
}

__device__ __forceinline__ unsigned int pk2bf(float a, float b) {
  __hip_bfloat16 lo = __float2bfloat16(a), hi = __float2bfloat16(b);
  return ((unsigned int)*(unsigned short*)&hi << 16) | *(unsigned short*)&lo;
}

// ---------------- elementwise convert f32 -> bf16 (x4 per thread) ----------------
__global__ __launch_bounds__(256) void convert_bf16_k(const float* __restrict__ in,
                                                      bf16* __restrict__ out) {
  int i = (blockIdx.x * 256 + threadIdx.x) * 4;
  float4 v = *(const float4*)&in[i];
  out[i + 0] = __float2bfloat16(v.x);
  out[i + 1] = __float2bfloat16(v.y);
  out[i + 2] = __float2bfloat16(v.z);
  out[i + 3] = __float2bfloat16(v.w);
}

// ---------------- tiled transpose + convert: in[K][N] f32 -> out[N][K] bf16 -------
__global__ __launch_bounds__(256) void transpose_convert_k(const float* __restrict__ in,
                                                           bf16* __restrict__ out,
                                                           int K, int N) {
  __shared__ float tile[32][33];
  int n0 = blockIdx.x * 32, k0 = blockIdx.y * 32;
  int tx = threadIdx.x, ty = threadIdx.y;
#pragma unroll
  for (int i = ty; i < 32; i += 8) tile[i][tx] = in[(size_t)(k0 + i) * N + n0 + tx];
  __syncthreads();
#pragma unroll
  for (int i = ty; i < 32; i += 8)
    out[(size_t)(n0 + i) * K + k0 + tx] = __float2bfloat16(tile[tx][i]);
}

// ---------------- 256x256 GEMM v2 (R16 verbatim): 64x128 wave tile; bf16 OUT -----
// 8 waves = 4(M) x 2(N); phase = ks half: 4 A-frags + 8 B-frags = 12 reads per
// 32 MFMA. Schedule (proven):
//   prologue: stage A[0]+B[0] (8 loads/thread), vmcnt(0), barrier.
//   p0 of t: reads ks0; stage A[t+1]+B[t+1] (8 loads); barrier; 32 MFMA.
//   p1 of t: reads ks1; vmcnt(0); barrier; 32 MFMA.
__global__ __launch_bounds__(512) void gemm256_k(const bf16* __restrict__ A,
                                                 const bf16* __restrict__ Bt,
                                                 bf16* __restrict__ C,
                                                 int M, int N, int K) {
  __shared__ bf16 Asm[2][256 * 64];
  __shared__ bf16 Bsm[2][256 * 64];
  const int tid = threadIdx.x;
  const int lane = tid & 63, wid = tid >> 6;
  const int fr = lane & 15, hi = lane >> 4;

  const int bid = blockIdx.y * gridDim.x + blockIdx.x;
  const int nwg = gridDim.x * gridDim.y;  // 192: %8==0, bijective
  const int swz = (bid & 7) * (nwg >> 3) + (bid >> 3);
  const int m0 = (swz % gridDim.x) * 256;
  const int n0 = (swz / gridDim.x) * 256;

  const bf16* Ag = A + (size_t)m0 * K;
  const bf16* Bg = Bt + (size_t)n0 * K;

  auto stageT = [&](const bf16* src, bf16* ldsBase, int k0) {
#pragma unroll
    for (int c = 0; c < 4; ++c) {
      int byte = tid * 16 + c * 8192;
      int row = byte >> 7;
      int col = byte & 127;
      int colSw = col ^ ((row & 7) << 4);
      gload16((const char*)(src + (size_t)row * K + k0) + colSw,
              (char*)ldsBase + byte);
    }
  };

  f32x4 acc[4][8];
#pragma unroll
  for (int m = 0; m < 4; ++m)
#pragma unroll
    for (int n = 0; n < 8; ++n) acc[m][n] = (f32x4){0.f, 0.f, 0.f, 0.f};

  const int r0 = (wid >> 1) * 64;
  const int c0 = (wid & 1) * 128;
  const int NT = K >> 6;

  stageT(Ag, &Asm[0][0], 0);
  stageT(Bg, &Bsm[0][0], 0);
  asm volatile("s_waitcnt vmcnt(0)" ::: "memory");
  __builtin_amdgcn_s_barrier();

  for (int t = 0; t < NT; ++t) {
    const int cur = t & 1;
    const int nxt = cur ^ 1;
    const int kn = (t + 1) << 6;
    const bool more = (t + 1) < NT;
#pragma unroll
    for (int p = 0; p < 2; ++p) {
      s16x8 af[4], bq[8];
#pragma unroll
      for (int m = 0; m < 4; ++m) {
        int r = r0 + m * 16 + fr;
        int cb = (p * 64 + hi * 16) ^ ((r & 7) << 4);
        af[m] = *(const s16x8*)((const char*)&Asm[cur][0] + r * 128 + cb);
      }
#pragma unroll
      for (int n = 0; n < 8; ++n) {
        int bn = c0 + n * 16 + fr;
        int cb = (p * 64 + hi * 16) ^ ((bn & 7) << 4);
        bq[n] = *(const s16x8*)((const char*)&Bsm[cur][0] + bn * 128 + cb);
      }
      if (p == 0) {
        if (more) {
          stageT(Ag, &Asm[nxt][0], kn);
          stageT(Bg, &Bsm[nxt][0], kn);
        }
      } else {
        asm volatile("s_waitcnt vmcnt(0)" ::: "memory");
      }
      __builtin_amdgcn_s_barrier();

      __builtin_amdgcn_s_setprio(1);
#pragma unroll
      for (int m = 0; m < 4; ++m)
#pragma unroll
        for (int n = 0; n < 8; ++n)
          acc[m][n] = mfma_16x16x32(af[m], bq[n], acc[m][n]);
      __builtin_amdgcn_s_setprio(0);
    }
  }

#pragma unroll
  for (int m = 0; m < 4; ++m)
#pragma unroll
    for (int n = 0; n < 8; ++n) {
      const int row = m0 + r0 + m * 16 + hi * 4;
      const int col = n0 + c0 + n * 16 + fr;
#pragma unroll
      for (int r = 0; r < 4; ++r)
        C[(size_t)(row + r) * N + col] = __float2bfloat16(acc[m][n][r]);
    }
}

// ---------------- 128x128 GEMM for Wo (R15 verbatim: proven), f32 out ------------
__global__ __launch_bounds__(256) void gemm128sq_k(const bf16* __restrict__ A,
                                                   const bf16* __restrict__ Bt,
                                                   float* __restrict__ C,
                                                   int M, int N, int K) {
  __shared__ bf16 Asm[2][128 * 64];
  __shared__ bf16 Bsm[2][128 * 64];
  const int tid = threadIdx.x;
  const int lane = tid & 63, wid = tid >> 6;
  const int fr = lane & 15, hi = lane >> 4;

  const int bid = blockIdx.y * gridDim.x + blockIdx.x;
  const int nwg = gridDim.x * gridDim.y;  // 512: %8==0, bijective
  const int swz = (bid & 7) * (nwg >> 3) + (bid >> 3);
  const int m0 = (swz % gridDim.x) * 128;
  const int n0 = (swz / gridDim.x) * 128;

  const bf16* Ag = A + (size_t)m0 * K;
  const bf16* Bg = Bt + (size_t)n0 * K;

  auto stageT = [&](const bf16* src, bf16* ldsBase, int k0) {
#pragma unroll
    for (int c = 0; c < 4; ++c) {
      int byte = tid * 16 + c * 4096;
      int row = byte >> 7;
      int col = byte & 127;
      int colSw = col ^ ((row & 7) << 4);
      gload16((const char*)(src + (size_t)row * K + k0) + colSw,
              (char*)ldsBase + byte);
    }
  };

  f32x4 acc[4][4];
#pragma unroll
  for (int m = 0; m < 4; ++m)
#pragma unroll
    for (int n = 0; n < 4; ++n) acc[m][n] = (f32x4){0.f, 0.f, 0.f, 0.f};

  const int r0 = (wid >> 1) * 64;
  const int c0 = (wid & 1) * 64;
  const int NT = K >> 6;

  stageT(Ag, &Asm[0][0], 0);
  stageT(Bg, &Bsm[0][0], 0);
  asm volatile("s_waitcnt vmcnt(0)" ::: "memory");
  __builtin_amdgcn_s_barrier();

  for (int t = 0; t < NT; ++t) {
    const int cur = t & 1;
    const int nxt = cur ^ 1;
    const int kn = (t + 1) << 6;
    const bool more = (t + 1) < NT;
#pragma unroll
    for (int p = 0; p < 2; ++p) {
      s16x8 af[4], bq[4];
#pragma unroll
      for (int m = 0; m < 4; ++m) {
        int r = r0 + m * 16 + fr;
        int cb = (p * 64 + hi * 16) ^ ((r & 7) << 4);
        af[m] = *(const s16x8*)((const char*)&Asm[cur][0] + r * 128 + cb);
      }
#pragma unroll
      for (int n = 0; n < 4; ++n) {
        int bn = c0 + n * 16 + fr;
        int cb = (p * 64 + hi * 16) ^ ((bn & 7) << 4);
        bq[n] = *(const s16x8*)((const char*)&Bsm[cur][0] + bn * 128 + cb);
      }
      if (p == 0) {
        if (more) {
          stageT(Ag, &Asm[nxt][0], kn);
          stageT(Bg, &Bsm[nxt][0], kn);
        }
      } else {
        asm volatile("s_waitcnt vmcnt(0)" ::: "memory");
      }
      __builtin_amdgcn_s_barrier();

      __builtin_amdgcn_s_setprio(1);
#pragma unroll
      for (int m = 0; m < 4; ++m)
#pragma unroll
        for (int n = 0; n < 4; ++n)
          acc[m][n] = mfma_16x16x32(af[m], bq[n], acc[m][n]);
      __builtin_amdgcn_s_setprio(0);
    }
  }

#pragma unroll
  for (int m = 0; m < 4; ++m)
#pragma unroll
    for (int n = 0; n < 4; ++n) {
      const int row = m0 + r0 + m * 16 + hi * 4;
      const int col = n0 + c0 + n * 16 + fr;
#pragma unroll
      for (int r = 0; r < 4; ++r)
        C[(size_t)(row + r) * N + col] = acc[m][n][r];
    }
}

// ---------------- RoPE for Q (bf16 in, pre-scaled by (1/sqrt(HD))*log2(e)) -------
__global__ __launch_bounds__(256) void rope_q_k(const bf16* __restrict__ qkv,
                                                const int* __restrict__ pos_ids,
                                                bf16* __restrict__ Q) {
  int idx = blockIdx.x * 256 + threadIdx.x;
  int i = idx & 63;
  int h = (idx >> 6) & 15;
  int s = (idx >> 10) & 2047;
  int b = idx >> 21;
  const float kscale = 0.12751841418861862f;  // (1/sqrt(128)) * log2(e)
  float pos = (float)pos_ids[b * S_LEN + s];
  float freq = exp2f((float)i * -0.31143075889569023f);
  float ang = pos * freq;
  float sn, cs;
  sincosf(ang, &sn, &cs);
  const bf16* src = qkv + (size_t)(b * S_LEN + s) * 3072 + h * HD + 2 * i;
  float e = __bfloat162float(src[0]), o = __bfloat162float(src[1]);
  bf16* dst = Q + ((size_t)(b * NH + h) * S_LEN + s) * HD + 2 * i;
  dst[0] = __float2bfloat16((e * cs - o * sn) * kscale);
  dst[1] = __float2bfloat16((e * sn + o * cs) * kscale);
}

// ---------------- RoPE for K (bf16 in) -------------------------------------------
__global__ __launch_bounds__(256) void rope_k_k(const bf16* __restrict__ qkv,
                                                const int* __restrict__ pos_ids,
                                                bf16* __restrict__ Kd) {
  int idx = blockIdx.x * 256 + threadIdx.x;
  int i = idx & 63;
  int kvh = (idx >> 6) & 3;
  int s = (idx >> 8) & 2047;
  int b = idx >> 19;
  float pos = (float)pos_ids[b * S_LEN + s];
  float freq = exp2f((float)i * -0.31143075889569023f);
  float ang = pos * freq;
  float sn, cs;
  sincosf(ang, &sn, &cs);
  const bf16* src = qkv + (size_t)(b * S_LEN + s) * 3072 + 2048 + kvh * HD + 2 * i;
  float e = __bfloat162float(src[0]), o = __bfloat162float(src[1]);
  bf16* dst = Kd + ((size_t)(b * NKV + kvh) * S_LEN + s) * HD + 2 * i;
  dst[0] = __float2bfloat16(e * cs - o * sn);
  dst[1] = __float2bfloat16(e * sn + o * cs);
}

// ---------------- V transpose via LDS tile (bf16 in, coalesced both sides) -------
__global__ __launch_bounds__(256) void v_trans_k(const bf16* __restrict__ qkv,
                                                 bf16* __restrict__ Vt) {
  __shared__ unsigned short tile[32][33];
  const int tx = threadIdx.x, ty = threadIdx.y;
  const int s0 = blockIdx.x * 32;
  const int d0 = blockIdx.y * 32;
  const int b = blockIdx.z >> 2, kvh = blockIdx.z & 3;
  const unsigned short* src = (const unsigned short*)qkv + 2560 + kvh * HD;
#pragma unroll
  for (int i = ty; i < 32; i += 8)
    tile[i][tx] = src[(size_t)(b * S_LEN + s0 + i) * 3072 + d0 + tx];
  __syncthreads();
  unsigned short* dst = (unsigned short*)Vt + (size_t)(b * NKV + kvh) * HD * S_LEN;
#pragma unroll
  for (int i = ty; i < 32; i += 8)
    dst[(size_t)(d0 + i) * S_LEN + s0 + tx] = tile[tx][i];
}

// ---------------- causal flash attention v9 (R11/R16 verbatim: proven 72us) ------
__global__ __launch_bounds__(256) void attn_k(const bf16* __restrict__ Q,
                                              const bf16* __restrict__ K,
                                              const bf16* __restrict__ Vt,
                                              bf16* __restrict__ Aout) {
  __shared__ bf16 Ks[2][64 * 128];
  __shared__ bf16 Vs[2][128 * 64];
  __shared__ bf16 Ps[4][16 * 64];

  const int lane = threadIdx.x & 63;
  const int wid = threadIdx.x >> 6;
  const int fr = lane & 15;
  const int hi = lane >> 4;
  const int pi = blockIdx.x, h = blockIdx.y, b = blockIdx.z;
  const int kvh = h >> 2;
  const bf16* Qh = Q + (size_t)(b * NH + h) * S_LEN * HD;
  const bf16* Kh = K + (size_t)(b * NKV + kvh) * S_LEN * HD;
  const bf16* Vh = Vt + (size_t)(b * NKV + kvh) * HD * S_LEN;

  const int oB = lane * 16;
  const int rinK = oB >> 8;
  const int rinV = oB >> 7;
  bf16* myP = &Ps[wid][0];
  const int pswz = (fr & 7) << 4;

  auto stageKV = [&](int bufi, int kv0) {
#pragma unroll
    for (int c = 0; c < 4; ++c) {
      int absr = wid * 16 + c * 4 + rinK;
      int colb = (oB & 255) ^ (((absr >> 2) & 7) << 4);  // matches K-read swizzle
      gload16((const char*)Kh + (size_t)(kv0 + absr) * 256 + colb,
              (char*)&Ks[bufi][0] + (wid * 16 + c * 4) * 256);
    }
#pragma unroll
    for (int c = 0; c < 4; ++c) {
      int absd = wid * 32 + c * 8 + rinV;
      int colb = (oB & 127) ^ ((absd & 7) << 4);
      gload16((const char*)Vh + (size_t)absd * (S_LEN * 2) + (size_t)kv0 * 2 + colb,
              (char*)&Vs[bufi][0] + (wid * 32 + c * 8) * 128);
    }
  };

#pragma unroll 1
  for (int t = 0; t < 2; ++t) {
    const int qb = t ? (31 - pi) : pi;
    const int q0w = qb * 64 + wid * 16;
    const int nsteps = qb + 1;

    s16x8 qf[4];
#pragma unroll
    for (int ks = 0; ks < 4; ++ks)
      qf[ks] = *(const s16x8*)&Qh[(size_t)(q0w + fr) * HD + ks * 32 + hi * 8];

    f32x4 o[8];
#pragma unroll
    for (int ds = 0; ds < 8; ++ds) o[ds] = (f32x4){0.f, 0.f, 0.f, 0.f};
    float lacc[4];
#pragma unroll
    for (int r = 0; r < 4; ++r) lacc[r] = 0.f;

    auto doStep = [&](int kv0, int bufc, auto LASTC) {
      constexpr bool LAST = decltype(LASTC)::value;
      f32x4 sg[4];
#pragma unroll
      for (int kv = 0; kv < 4; ++kv) {
        f32x4 a = (f32x4){0.f, 0.f, 0.f, 0.f};
        const int row = 4 * fr + kv;  // sg[kv] col fr <-> K row 4*fr+kv
#pragma unroll
        for (int ks = 0; ks < 4; ++ks) {
          int cb = (ks * 64 + hi * 16) ^ (((row >> 2) & 7) << 4);
          s16x8 kf = *(const s16x8*)((const char*)&Ks[bufc][0] + row * 256 + cb);
          a = mfma_16x16x32(qf[ks], kf, a);
        }
        sg[kv] = a;
      }

#pragma unroll
      for (int r = 0; r < 4; ++r) {
        float p0 = __builtin_exp2f(sg[0][r]);
        float p1 = __builtin_exp2f(sg[1][r]);
        float p2 = __builtin_exp2f(sg[2][r]);
        float p3 = __builtin_exp2f(sg[3][r]);
        if (LAST) {  // diagonal tile: k = kv0 + 4*fr + kv
          const int qrow = q0w + hi * 4 + r;
          const int kb = kv0 + 4 * fr;
          p0 = (kb <= qrow) ? p0 : 0.f;
          p1 = (kb + 1 <= qrow) ? p1 : 0.f;
          p2 = (kb + 2 <= qrow) ? p2 : 0.f;
          p3 = (kb + 3 <= qrow) ? p3 : 0.f;
        }
        lacc[r] += (p0 + p1) + (p2 + p3);
        const int prow = hi * 4 + r;
        uint2 pv;
        pv.x = pk2bf(p0, p1);
        pv.y = pk2bf(p2, p3);
        *(uint2*)((char*)myP + prow * 128 + ((fr * 8) ^ ((prow & 7) << 4))) = pv;
      }
      __builtin_amdgcn_wave_barrier();

      s16x8 pf[2];
#pragma unroll
      for (int g = 0; g < 2; ++g) {
        int cb = (g * 64 + hi * 16) ^ pswz;
        pf[g] = *(const s16x8*)((const char*)myP + fr * 128 + cb);
      }
      __builtin_amdgcn_wave_barrier();
#pragma unroll
      for (int ds = 0; ds < 8; ++ds) {
#pragma unroll
        for (int g = 0; g < 2; ++g) {
          int d = ds * 16 + fr;
          int cb = (g * 64 + hi * 16) ^ ((d & 7) << 4);
          s16x8 vf = *(const s16x8*)((const char*)&Vs[bufc][0] + d * 128 + cb);
          o[ds] = mfma_16x16x32(pf[g], vf, o[ds]);
        }
      }
    };

    int buf = 0;
    stageKV(0, 0);
    __syncthreads();

    for (int s = 0; s < nsteps - 1; ++s) {
      stageKV(buf ^ 1, s * 64 + 64);
      doStep(s * 64, buf, FalseT{});
      __syncthreads();
      buf ^= 1;
    }
    doStep((nsteps - 1) * 64, buf, TrueT{});
    __syncthreads();

#pragma unroll
    for (int r = 0; r < 4; ++r) {
      float l = lacc[r];
      l += __shfl_xor(l, 1, 16);
      l += __shfl_xor(l, 2, 16);
      l += __shfl_xor(l, 4, 16);
      l += __shfl_xor(l, 8, 16);
      float inv = 1.0f / l;
      const int srow = q0w + hi * 4 + r;
      bf16* orow = Aout + ((size_t)b * S_LEN + srow) * HID_D + h * HD;
#pragma unroll
      for (int ds = 0; ds < 8; ++ds)
        orow[ds * 16 + fr] = __float2bfloat16(o[ds][r] * inv);
    }
  }
}

extern "C" void kernel_launch(void* const* d_in, const int* in_sizes, int n_in,
                              void* d_out, int out_size, void* d_ws, size_t ws_size,
                              hipStream_t stream) {
  const float* x = (const float*)d_in[0];
  const int* pos = (const int*)d_in[1];
  // d_in[2] attention_mask: known causal, applied analytically
  const float* Wq = (const float*)d_in[3];
  const float* Wk = (const float*)d_in[4];
  const float* Wv = (const float*)d_in[5];
  const float* Wo = (const float*)d_in[6];
  float* out = (float*)d_out;

  char* ws = (char*)d_ws;
  size_t off = 0;
  auto alloc = [&](size_t bytes) {
    char* p = ws + off;
    off += (bytes + 255) & ~(size_t)255;
    return p;
  };
  bf16* xb = (bf16*)alloc((size_t)4096 * 2048 * 2);
  bf16* WqkvT = (bf16*)alloc((size_t)3072 * 2048 * 2);
  bf16* WoT = (bf16*)alloc((size_t)2048 * 2048 * 2);
  bf16* qkv = (bf16*)alloc((size_t)4096 * 3072 * 2);   // bf16 intermediate
  bf16* Qb = (bf16*)alloc((size_t)BATCH * NH * S_LEN * HD * 2);
  bf16* Kb = (bf16*)alloc((size_t)BATCH * NKV * S_LEN * HD * 2);
  bf16* Vtb = (bf16*)alloc((size_t)BATCH * NKV * HD * S_LEN * 2);
  bf16* aout = (bf16*)qkv;  // alias: qkv dead after rope/v_trans

  convert_bf16_k<<<8192, 256, 0, stream>>>(x, xb);
  dim3 tb(32, 8);
  transpose_convert_k<<<dim3(64, 64), tb, 0, stream>>>(Wq, WqkvT, 2048, 2048);
  transpose_convert_k<<<dim3(16, 64), tb, 0, stream>>>(Wk, WqkvT + (size_t)2048 * 2048, 2048, 512);
  transpose_convert_k<<<dim3(16, 64), tb, 0, stream>>>(Wv, WqkvT + (size_t)2560 * 2048, 2048, 512);
  transpose_convert_k<<<dim3(64, 64), tb, 0, stream>>>(Wo, WoT, 2048, 2048);

  gemm256_k<<<dim3(16, 12), 512, 0, stream>>>(xb, WqkvT, qkv, 4096, 3072, 2048);

  rope_q_k<<<16384, 256, 0, stream>>>(qkv, pos, Qb);
  rope_k_k<<<4096, 256, 0, stream>>>(qkv, pos, Kb);
  v_trans_k<<<dim3(64, 4, 8), tb, 0, stream>>>(qkv, Vtb);

  attn_k<<<dim3(16, NH, BATCH), 256, 0, stream>>>(Qb, Kb, Vtb, aout);

  gemm128sq_k<<<dim3(32, 16), 256, 0, stream>>>(aout, WoT, out, 4096, 2048, 2048);
}

// Round 21
// 190.037 us; speedup vs baseline: 1.3515x; 1.0549x over previous
//
#include <hip/hip_runtime.h>
#include <hip/hip_bf16.h>

#define S_LEN 2048
#define HID_D 2048
#define NH 16
#define NKV 4
#define HD 128
#define BATCH 2

typedef __hip_bfloat16 bf16;
using f32x4 = __attribute__((ext_vector_type(4))) float;
using s16x8 = __attribute__((ext_vector_type(8))) short;

struct TrueT { static constexpr bool value = true; };
struct FalseT { static constexpr bool value = false; };

__device__ __forceinline__ f32x4 mfma_16x16x32(s16x8 a, s16x8 b, f32x4 c) {
  return __builtin_amdgcn_mfma_f32_16x16x32_bf16(a, b, c, 0, 0, 0);
}

__device__ __forceinline__ void gload16(const void* g, void* l) {
  __builtin_amdgcn_global_load_lds(
      (const __attribute__((address_space(1))) void*)g,
      (__attribute__((address_space(3))) void*)l, 16, 0, 0);
}

__device__ __forceinline__ unsigned int pk2bf(float a, float b) {
  __hip_bfloat16 lo = __float2bfloat16(a), hi = __float2bfloat16(b);
  return ((unsigned int)*(unsigned short*)&hi << 16) | *(unsigned short*)&lo;
}

// ---------------- prep: x convert + all 4 weight transposes in ONE dispatch ------
// blocks [0,10240): transpose tiles, bx=x%160 (0-63 Wq | 64-79 Wk | 80-95 Wv |
// 96-159 Wo), by=x/160 -> k0. blocks [10240,18432): f32->bf16 convert of x.
__global__ __launch_bounds__(256) void prep_k(const float* __restrict__ x,
                                              const float* __restrict__ Wq,
                                              const float* __restrict__ Wk,
                                              const float* __restrict__ Wv,
                                              const float* __restrict__ Wo,
                                              bf16* __restrict__ xb,
                                              bf16* __restrict__ WqkvT,
                                              bf16* __restrict__ WoT) {
  __shared__ float tile[32][33];
  const int tid = threadIdx.x;
  const int X = blockIdx.x;
  if (X < 10240) {
    const int bx = X % 160, by = X / 160;
    const float* src;
    bf16* dst;
    int N, n0;
    if (bx < 64) { src = Wq; dst = WqkvT; N = 2048; n0 = bx * 32; }
    else if (bx < 80) { src = Wk; dst = WqkvT + (size_t)2048 * 2048; N = 512; n0 = (bx - 64) * 32; }
    else if (bx < 96) { src = Wv; dst = WqkvT + (size_t)2560 * 2048; N = 512; n0 = (bx - 80) * 32; }
    else { src = Wo; dst = WoT; N = 2048; n0 = (bx - 96) * 32; }
    const int k0 = by * 32;
    const int tx = tid & 31, ty = tid >> 5;
#pragma unroll
    for (int i = ty; i < 32; i += 8) tile[i][tx] = src[(size_t)(k0 + i) * N + n0 + tx];
    __syncthreads();
#pragma unroll
    for (int i = ty; i < 32; i += 8)
      dst[(size_t)(n0 + i) * 2048 + k0 + tx] = __float2bfloat16(tile[tx][i]);
  } else {
    int i = ((X - 10240) * 256 + tid) * 4;
    float4 v = *(const float4*)&x[i];
    xb[i + 0] = __float2bfloat16(v.x);
    xb[i + 1] = __float2bfloat16(v.y);
    xb[i + 2] = __float2bfloat16(v.z);
    xb[i + 3] = __float2bfloat16(v.w);
  }
}

// ---------------- 256x256 GEMM v2 (R16 verbatim): 64x128 wave tile; bf16 OUT -----
__global__ __launch_bounds__(512) void gemm256_k(const bf16* __restrict__ A,
                                                 const bf16* __restrict__ Bt,
                                                 bf16* __restrict__ C,
                                                 int M, int N, int K) {
  __shared__ bf16 Asm[2][256 * 64];
  __shared__ bf16 Bsm[2][256 * 64];
  const int tid = threadIdx.x;
  const int lane = tid & 63, wid = tid >> 6;
  const int fr = lane & 15, hi = lane >> 4;

  const int bid = blockIdx.y * gridDim.x + blockIdx.x;
  const int nwg = gridDim.x * gridDim.y;  // 192: %8==0, bijective
  const int swz = (bid & 7) * (nwg >> 3) + (bid >> 3);
  const int m0 = (swz % gridDim.x) * 256;
  const int n0 = (swz / gridDim.x) * 256;

  const bf16* Ag = A + (size_t)m0 * K;
  const bf16* Bg = Bt + (size_t)n0 * K;

  auto stageT = [&](const bf16* src, bf16* ldsBase, int k0) {
#pragma unroll
    for (int c = 0; c < 4; ++c) {
      int byte = tid * 16 + c * 8192;
      int row = byte >> 7;
      int col = byte & 127;
      int colSw = col ^ ((row & 7) << 4);
      gload16((const char*)(src + (size_t)row * K + k0) + colSw,
              (char*)ldsBase + byte);
    }
  };

  f32x4 acc[4][8];
#pragma unroll
  for (int m = 0; m < 4; ++m)
#pragma unroll
    for (int n = 0; n < 8; ++n) acc[m][n] = (f32x4){0.f, 0.f, 0.f, 0.f};

  const int r0 = (wid >> 1) * 64;
  const int c0 = (wid & 1) * 128;
  const int NT = K >> 6;

  stageT(Ag, &Asm[0][0], 0);
  stageT(Bg, &Bsm[0][0], 0);
  asm volatile("s_waitcnt vmcnt(0)" ::: "memory");
  __builtin_amdgcn_s_barrier();

  for (int t = 0; t < NT; ++t) {
    const int cur = t & 1;
    const int nxt = cur ^ 1;
    const int kn = (t + 1) << 6;
    const bool more = (t + 1) < NT;
#pragma unroll
    for (int p = 0; p < 2; ++p) {
      s16x8 af[4], bq[8];
#pragma unroll
      for (int m = 0; m < 4; ++m) {
        int r = r0 + m * 16 + fr;
        int cb = (p * 64 + hi * 16) ^ ((r & 7) << 4);
        af[m] = *(const s16x8*)((const char*)&Asm[cur][0] + r * 128 + cb);
      }
#pragma unroll
      for (int n = 0; n < 8; ++n) {
        int bn = c0 + n * 16 + fr;
        int cb = (p * 64 + hi * 16) ^ ((bn & 7) << 4);
        bq[n] = *(const s16x8*)((const char*)&Bsm[cur][0] + bn * 128 + cb);
      }
      if (p == 0) {
        if (more) {
          stageT(Ag, &Asm[nxt][0], kn);
          stageT(Bg, &Bsm[nxt][0], kn);
        }
      } else {
        asm volatile("s_waitcnt vmcnt(0)" ::: "memory");
      }
      __builtin_amdgcn_s_barrier();

      __builtin_amdgcn_s_setprio(1);
#pragma unroll
      for (int m = 0; m < 4; ++m)
#pragma unroll
        for (int n = 0; n < 8; ++n)
          acc[m][n] = mfma_16x16x32(af[m], bq[n], acc[m][n]);
      __builtin_amdgcn_s_setprio(0);
    }
  }

#pragma unroll
  for (int m = 0; m < 4; ++m)
#pragma unroll
    for (int n = 0; n < 8; ++n) {
      const int row = m0 + r0 + m * 16 + hi * 4;
      const int col = n0 + c0 + n * 16 + fr;
#pragma unroll
      for (int r = 0; r < 4; ++r)
        C[(size_t)(row + r) * N + col] = __float2bfloat16(acc[m][n][r]);
    }
}

// ---------------- 128x128 GEMM for Wo (R15 verbatim: proven), f32 out ------------
__global__ __launch_bounds__(256) void gemm128sq_k(const bf16* __restrict__ A,
                                                   const bf16* __restrict__ Bt,
                                                   float* __restrict__ C,
                                                   int M, int N, int K) {
  __shared__ bf16 Asm[2][128 * 64];
  __shared__ bf16 Bsm[2][128 * 64];
  const int tid = threadIdx.x;
  const int lane = tid & 63, wid = tid >> 6;
  const int fr = lane & 15, hi = lane >> 4;

  const int bid = blockIdx.y * gridDim.x + blockIdx.x;
  const int nwg = gridDim.x * gridDim.y;  // 512: %8==0, bijective
  const int swz = (bid & 7) * (nwg >> 3) + (bid >> 3);
  const int m0 = (swz % gridDim.x) * 128;
  const int n0 = (swz / gridDim.x) * 128;

  const bf16* Ag = A + (size_t)m0 * K;
  const bf16* Bg = Bt + (size_t)n0 * K;

  auto stageT = [&](const bf16* src, bf16* ldsBase, int k0) {
#pragma unroll
    for (int c = 0; c < 4; ++c) {
      int byte = tid * 16 + c * 4096;
      int row = byte >> 7;
      int col = byte & 127;
      int colSw = col ^ ((row & 7) << 4);
      gload16((const char*)(src + (size_t)row * K + k0) + colSw,
              (char*)ldsBase + byte);
    }
  };

  f32x4 acc[4][4];
#pragma unroll
  for (int m = 0; m < 4; ++m)
#pragma unroll
    for (int n = 0; n < 4; ++n) acc[m][n] = (f32x4){0.f, 0.f, 0.f, 0.f};

  const int r0 = (wid >> 1) * 64;
  const int c0 = (wid & 1) * 64;
  const int NT = K >> 6;

  stageT(Ag, &Asm[0][0], 0);
  stageT(Bg, &Bsm[0][0], 0);
  asm volatile("s_waitcnt vmcnt(0)" ::: "memory");
  __builtin_amdgcn_s_barrier();

  for (int t = 0; t < NT; ++t) {
    const int cur = t & 1;
    const int nxt = cur ^ 1;
    const int kn = (t + 1) << 6;
    const bool more = (t + 1) < NT;
#pragma unroll
    for (int p = 0; p < 2; ++p) {
      s16x8 af[4], bq[4];
#pragma unroll
      for (int m = 0; m < 4; ++m) {
        int r = r0 + m * 16 + fr;
        int cb = (p * 64 + hi * 16) ^ ((r & 7) << 4);
        af[m] = *(const s16x8*)((const char*)&Asm[cur][0] + r * 128 + cb);
      }
#pragma unroll
      for (int n = 0; n < 4; ++n) {
        int bn = c0 + n * 16 + fr;
        int cb = (p * 64 + hi * 16) ^ ((bn & 7) << 4);
        bq[n] = *(const s16x8*)((const char*)&Bsm[cur][0] + bn * 128 + cb);
      }
      if (p == 0) {
        if (more) {
          stageT(Ag, &Asm[nxt][0], kn);
          stageT(Bg, &Bsm[nxt][0], kn);
        }
      } else {
        asm volatile("s_waitcnt vmcnt(0)" ::: "memory");
      }
      __builtin_amdgcn_s_barrier();

      __builtin_amdgcn_s_setprio(1);
#pragma unroll
      for (int m = 0; m < 4; ++m)
#pragma unroll
        for (int n = 0; n < 4; ++n)
          acc[m][n] = mfma_16x16x32(af[m], bq[n], acc[m][n]);
      __builtin_amdgcn_s_setprio(0);
    }
  }

#pragma unroll
  for (int m = 0; m < 4; ++m)
#pragma unroll
    for (int n = 0; n < 4; ++n) {
      const int row = m0 + r0 + m * 16 + hi * 4;
      const int col = n0 + c0 + n * 16 + fr;
#pragma unroll
      for (int r = 0; r < 4; ++r)
        C[(size_t)(row + r) * N + col] = acc[m][n][r];
    }
}

// ---------------- post-QKV: rope_q + rope_k + v_trans in ONE dispatch ------------
// blocks [0,16384): rope Q | [16384,20480): rope K | [20480,22528): V transpose.
__global__ __launch_bounds__(256) void postq_k(const bf16* __restrict__ qkv,
                                               const int* __restrict__ pos_ids,
                                               bf16* __restrict__ Q,
                                               bf16* __restrict__ Kd,
                                               bf16* __restrict__ Vt) {
  __shared__ unsigned short vtile[32][33];
  const int tid = threadIdx.x;
  const int X = blockIdx.x;
  const float kscale = 0.12751841418861862f;  // (1/sqrt(128)) * log2(e)

  if (X < 16384) {                            // ---- RoPE Q (pre-scaled) ----
    int idx = X * 256 + tid;
    int i = idx & 63;
    int h = (idx >> 6) & 15;
    int s = (idx >> 10) & 2047;
    int b = idx >> 21;
    float pos = (float)pos_ids[b * S_LEN + s];
    float freq = exp2f((float)i * -0.31143075889569023f);
    float ang = pos * freq;
    float sn, cs;
    sincosf(ang, &sn, &cs);
    const bf16* src = qkv + (size_t)(b * S_LEN + s) * 3072 + h * HD + 2 * i;
    float e = __bfloat162float(src[0]), o = __bfloat162float(src[1]);
    bf16* dst = Q + ((size_t)(b * NH + h) * S_LEN + s) * HD + 2 * i;
    dst[0] = __float2bfloat16((e * cs - o * sn) * kscale);
    dst[1] = __float2bfloat16((e * sn + o * cs) * kscale);
  } else if (X < 20480) {                     // ---- RoPE K ----
    int idx = (X - 16384) * 256 + tid;
    int i = idx & 63;
    int kvh = (idx >> 6) & 3;
    int s = (idx >> 8) & 2047;
    int b = idx >> 19;
    float pos = (float)pos_ids[b * S_LEN + s];
    float freq = exp2f((float)i * -0.31143075889569023f);
    float ang = pos * freq;
    float sn, cs;
    sincosf(ang, &sn, &cs);
    const bf16* src = qkv + (size_t)(b * S_LEN + s) * 3072 + 2048 + kvh * HD + 2 * i;
    float e = __bfloat162float(src[0]), o = __bfloat162float(src[1]);
    bf16* dst = Kd + ((size_t)(b * NKV + kvh) * S_LEN + s) * HD + 2 * i;
    dst[0] = __float2bfloat16(e * cs - o * sn);
    dst[1] = __float2bfloat16(e * sn + o * cs);
  } else {                                    // ---- V transpose (LDS tile) ----
    const int vb = X - 20480;                 // [0,2048): 64 s-blk x 4 d-blk x 8 z
    const int s0 = (vb & 63) * 32;
    const int d0 = ((vb >> 6) & 3) * 32;
    const int z = vb >> 8;
    const int b = z >> 2, kvh = z & 3;
    const int tx = tid & 31, ty = tid >> 5;
    const unsigned short* src = (const unsigned short*)qkv + 2560 + kvh * HD;
#pragma unroll
    for (int i = ty; i < 32; i += 8)
      vtile[i][tx] = src[(size_t)(b * S_LEN + s0 + i) * 3072 + d0 + tx];
    __syncthreads();
    unsigned short* dst = (unsigned short*)Vt + (size_t)(b * NKV + kvh) * HD * S_LEN;
#pragma unroll
    for (int i = ty; i < 32; i += 8)
      dst[(size_t)(d0 + i) * S_LEN + s0 + tx] = vtile[tx][i];
  }
}

// ---------------- causal flash attention v9 (R11/R16 verbatim: proven 72us) ------
__global__ __launch_bounds__(256) void attn_k(const bf16* __restrict__ Q,
                                              const bf16* __restrict__ K,
                                              const bf16* __restrict__ Vt,
                                              bf16* __restrict__ Aout) {
  __shared__ bf16 Ks[2][64 * 128];
  __shared__ bf16 Vs[2][128 * 64];
  __shared__ bf16 Ps[4][16 * 64];

  const int lane = threadIdx.x & 63;
  const int wid = threadIdx.x >> 6;
  const int fr = lane & 15;
  const int hi = lane >> 4;
  const int pi = blockIdx.x, h = blockIdx.y, b = blockIdx.z;
  const int kvh = h >> 2;
  const bf16* Qh = Q + (size_t)(b * NH + h) * S_LEN * HD;
  const bf16* Kh = K + (size_t)(b * NKV + kvh) * S_LEN * HD;
  const bf16* Vh = Vt + (size_t)(b * NKV + kvh) * HD * S_LEN;

  const int oB = lane * 16;
  const int rinK = oB >> 8;
  const int rinV = oB >> 7;
  bf16* myP = &Ps[wid][0];
  const int pswz = (fr & 7) << 4;

  auto stageKV = [&](int bufi, int kv0) {
#pragma unroll
    for (int c = 0; c < 4; ++c) {
      int absr = wid * 16 + c * 4 + rinK;
      int colb = (oB & 255) ^ (((absr >> 2) & 7) << 4);  // matches K-read swizzle
      gload16((const char*)Kh + (size_t)(kv0 + absr) * 256 + colb,
              (char*)&Ks[bufi][0] + (wid * 16 + c * 4) * 256);
    }
#pragma unroll
    for (int c = 0; c < 4; ++c) {
      int absd = wid * 32 + c * 8 + rinV;
      int colb = (oB & 127) ^ ((absd & 7) << 4);
      gload16((const char*)Vh + (size_t)absd * (S_LEN * 2) + (size_t)kv0 * 2 + colb,
              (char*)&Vs[bufi][0] + (wid * 32 + c * 8) * 128);
    }
  };

#pragma unroll 1
  for (int t = 0; t < 2; ++t) {
    const int qb = t ? (31 - pi) : pi;
    const int q0w = qb * 64 + wid * 16;
    const int nsteps = qb + 1;

    s16x8 qf[4];
#pragma unroll
    for (int ks = 0; ks < 4; ++ks)
      qf[ks] = *(const s16x8*)&Qh[(size_t)(q0w + fr) * HD + ks * 32 + hi * 8];

    f32x4 o[8];
#pragma unroll
    for (int ds = 0; ds < 8; ++ds) o[ds] = (f32x4){0.f, 0.f, 0.f, 0.f};
    float lacc[4];
#pragma unroll
    for (int r = 0; r < 4; ++r) lacc[r] = 0.f;

    auto doStep = [&](int kv0, int bufc, auto LASTC) {
      constexpr bool LAST = decltype(LASTC)::value;
      f32x4 sg[4];
#pragma unroll
      for (int kv = 0; kv < 4; ++kv) {
        f32x4 a = (f32x4){0.f, 0.f, 0.f, 0.f};
        const int row = 4 * fr + kv;  // sg[kv] col fr <-> K row 4*fr+kv
#pragma unroll
        for (int ks = 0; ks < 4; ++ks) {
          int cb = (ks * 64 + hi * 16) ^ (((row >> 2) & 7) << 4);
          s16x8 kf = *(const s16x8*)((const char*)&Ks[bufc][0] + row * 256 + cb);
          a = mfma_16x16x32(qf[ks], kf, a);
        }
        sg[kv] = a;
      }

#pragma unroll
      for (int r = 0; r < 4; ++r) {
        float p0 = __builtin_exp2f(sg[0][r]);
        float p1 = __builtin_exp2f(sg[1][r]);
        float p2 = __builtin_exp2f(sg[2][r]);
        float p3 = __builtin_exp2f(sg[3][r]);
        if (LAST) {  // diagonal tile: k = kv0 + 4*fr + kv
          const int qrow = q0w + hi * 4 + r;
          const int kb = kv0 + 4 * fr;
          p0 = (kb <= qrow) ? p0 : 0.f;
          p1 = (kb + 1 <= qrow) ? p1 : 0.f;
          p2 = (kb + 2 <= qrow) ? p2 : 0.f;
          p3 = (kb + 3 <= qrow) ? p3 : 0.f;
        }
        lacc[r] += (p0 + p1) + (p2 + p3);
        const int prow = hi * 4 + r;
        uint2 pv;
        pv.x = pk2bf(p0, p1);
        pv.y = pk2bf(p2, p3);
        *(uint2*)((char*)myP + prow * 128 + ((fr * 8) ^ ((prow & 7) << 4))) = pv;
      }
      __builtin_amdgcn_wave_barrier();

      s16x8 pf[2];
#pragma unroll
      for (int g = 0; g < 2; ++g) {
        int cb = (g * 64 + hi * 16) ^ pswz;
        pf[g] = *(const s16x8*)((const char*)myP + fr * 128 + cb);
      }
      __builtin_amdgcn_wave_barrier();
#pragma unroll
      for (int ds = 0; ds < 8; ++ds) {
#pragma unroll
        for (int g = 0; g < 2; ++g) {
          int d = ds * 16 + fr;
          int cb = (g * 64 + hi * 16) ^ ((d & 7) << 4);
          s16x8 vf = *(const s16x8*)((const char*)&Vs[bufc][0] + d * 128 + cb);
          o[ds] = mfma_16x16x32(pf[g], vf, o[ds]);
        }
      }
    };

    int buf = 0;
    stageKV(0, 0);
    __syncthreads();

    for (int s = 0; s < nsteps - 1; ++s) {
      stageKV(buf ^ 1, s * 64 + 64);
      doStep(s * 64, buf, FalseT{});
      __syncthreads();
      buf ^= 1;
    }
    doStep((nsteps - 1) * 64, buf, TrueT{});
    __syncthreads();

#pragma unroll
    for (int r = 0; r < 4; ++r) {
      float l = lacc[r];
      l += __shfl_xor(l, 1, 16);
      l += __shfl_xor(l, 2, 16);
      l += __shfl_xor(l, 4, 16);
      l += __shfl_xor(l, 8, 16);
      float inv = 1.0f / l;
      const int srow = q0w + hi * 4 + r;
      bf16* orow = Aout + ((size_t)b * S_LEN + srow) * HID_D + h * HD;
#pragma unroll
      for (int ds = 0; ds < 8; ++ds)
        orow[ds * 16 + fr] = __float2bfloat16(o[ds][r] * inv);
    }
  }
}

extern "C" void kernel_launch(void* const* d_in, const int* in_sizes, int n_in,
                              void* d_out, int out_size, void* d_ws, size_t ws_size,
                              hipStream_t stream) {
  const float* x = (const float*)d_in[0];
  const int* pos = (const int*)d_in[1];
  // d_in[2] attention_mask: known causal, applied analytically
  const float* Wq = (const float*)d_in[3];
  const float* Wk = (const float*)d_in[4];
  const float* Wv = (const float*)d_in[5];
  const float* Wo = (const float*)d_in[6];
  float* out = (float*)d_out;

  char* ws = (char*)d_ws;
  size_t off = 0;
  auto alloc = [&](size_t bytes) {
    char* p = ws + off;
    off += (bytes + 255) & ~(size_t)255;
    return p;
  };
  bf16* xb = (bf16*)alloc((size_t)4096 * 2048 * 2);
  bf16* WqkvT = (bf16*)alloc((size_t)3072 * 2048 * 2);
  bf16* WoT = (bf16*)alloc((size_t)2048 * 2048 * 2);
  bf16* qkv = (bf16*)alloc((size_t)4096 * 3072 * 2);   // bf16 intermediate
  bf16* Qb = (bf16*)alloc((size_t)BATCH * NH * S_LEN * HD * 2);
  bf16* Kb = (bf16*)alloc((size_t)BATCH * NKV * S_LEN * HD * 2);
  bf16* Vtb = (bf16*)alloc((size_t)BATCH * NKV * HD * S_LEN * 2);
  bf16* aout = (bf16*)qkv;  // alias: qkv dead after postq

  prep_k<<<18432, 256, 0, stream>>>(x, Wq, Wk, Wv, Wo, xb, WqkvT, WoT);

  gemm256_k<<<dim3(16, 12), 512, 0, stream>>>(xb, WqkvT, qkv, 4096, 3072, 2048);

  postq_k<<<22528, 256, 0, stream>>>(qkv, pos, Qb, Kb, Vtb);

  attn_k<<<dim3(16, NH, BATCH), 256, 0, stream>>>(Qb, Kb, Vtb, aout);

  gemm128sq_k<<<dim3(32, 16), 256, 0, stream>>>(aout, WoT, out, 4096, 2048, 2048);
}